// Round 5
// baseline (108.829 us; speedup 1.0000x reference)
//
#include <hip/hip_runtime.h>
#include <hip/hip_bf16.h>

// Problem constants (B, L, H, HS, OUT) = (4, 512, 768, 64, 16)
#define Bc   4
#define Lc   512
#define Hc   768
#define HSc  64
#define OUTc 16
#define Pc   131328   // L*(L+1)/2
#define KSEG 192      // K quarter (768/4)
#define MTOK 8        // tokens per block in qk kernel

typedef float floatx4 __attribute__((ext_vector_type(4)));

// Workspace layout (floats): q@0, k@131072, A@262144, E@294912

// Kernel 1: fused q/k projection + per-token A/E projections.
// Grid: 256 blocks x 512 threads (8 waves); block = 8 tokens.
// Wave wu: half = wu&1 (q or k cols), kseg = wu>>1 (K range [kseg*192,+192)).
// 8 accumulators/thread amortize each W load 8x -> W L2 traffic 100 MB.
// Double-buffered 16-deep W prefetch; x loads wave-uniform -> scalar s_load.
__global__ __launch_bounds__(512) void qk_proj_kernel(
    const float* __restrict__ x,
    const float* __restrict__ Wq, const float* __restrict__ bq,
    const float* __restrict__ Wk, const float* __restrict__ bk,
    const float* __restrict__ Wb, const float* __restrict__ bb,
    float* __restrict__ qws, float* __restrict__ kws,
    float* __restrict__ Aws, float* __restrict__ Ews)
{
    __shared__ float lds_p[4][MTOK][128];   // [kseg][local token][q|k]
    __shared__ float lds_c[MTOK][128];      // combined q|k per token

    const int tid = threadIdx.x;
    const int wu  = __builtin_amdgcn_readfirstlane(tid >> 6);  // wave id 0..7
    const int half = wu & 1;                                   // 0=q, 1=k
    const int kseg = wu >> 1;                                  // 0..3
    const int col  = tid & 63;
    const int tok_base = blockIdx.x * MTOK;

    const float* Wp = half ? Wk : Wq;                          // wave-uniform
    const float* wp = Wp + (size_t)kseg * KSEG * HSc + col;
    const float* xr = x + (size_t)tok_base * Hc + kseg * KSEG; // uniform -> s_load

    float acc[MTOK];
    #pragma unroll
    for (int t = 0; t < MTOK; ++t) acc[t] = 0.f;

    float wA[16], wB[16];
    #pragma unroll
    for (int u = 0; u < 16; ++u) wA[u] = wp[u * HSc];

    #pragma unroll 1
    for (int j0 = 0; j0 < KSEG; j0 += 32) {
        #pragma unroll
        for (int u = 0; u < 16; ++u) wB[u] = wp[(j0 + 16 + u) * HSc];
        #pragma unroll
        for (int u = 0; u < 16; ++u) {
            const int jj = j0 + u;
            #pragma unroll
            for (int t = 0; t < MTOK; ++t)
                acc[t] += xr[t * Hc + jj] * wA[u];
        }
        if (j0 + 32 < KSEG) {
            #pragma unroll
            for (int u = 0; u < 16; ++u) wA[u] = wp[(j0 + 32 + u) * HSc];
        }
        #pragma unroll
        for (int u = 0; u < 16; ++u) {
            const int jj = j0 + 16 + u;
            #pragma unroll
            for (int t = 0; t < MTOK; ++t)
                acc[t] += xr[t * Hc + jj] * wB[u];
        }
    }

    const int n = half * 64 + col;
    #pragma unroll
    for (int t = 0; t < MTOK; ++t) lds_p[kseg][t][n] = acc[t];
    __syncthreads();

    // Combine 4 K-segments + bias; store q/k; keep combined copy for phase B.
    #pragma unroll
    for (int i = tid; i < MTOK * 128; i += 512) {
        const int t = i >> 7;
        const int c = i & 127;
        float v = lds_p[0][t][c] + lds_p[1][t][c] + lds_p[2][t][c] + lds_p[3][t][c];
        const int cc = c & 63;
        if (c < 64) { v += bq[cc]; qws[(size_t)(tok_base + t) * HSc + cc] = v; }
        else        { v += bk[cc]; kws[(size_t)(tok_base + t) * HSc + cc] = v; }
        lds_c[t][c] = v;
    }
    __syncthreads();

    // Phase B: A[t] = q@Wb[0:64]; E[t] = q@Wb[128:192] + k@(Wb[64:128]+Wb[192:256]) + bb
    if (tid < MTOK * 32) {
        const int t = tid >> 5;
        const int c = tid & 31;
        const int tok = tok_base + t;
        const float* row = lds_c[t];
        if (c < 16) {
            float a = 0.f;
            #pragma unroll 8
            for (int h = 0; h < 64; ++h)
                a += row[h] * Wb[h * OUTc + c];
            Aws[(size_t)tok * OUTc + c] = a;
        } else {
            const int o = c - 16;
            float ev = bb[o];
            #pragma unroll 8
            for (int h = 0; h < 64; ++h) {
                ev += row[h]      * Wb[(128 + h) * OUTc + o];
                ev += row[64 + h] * (Wb[(64 + h) * OUTc + o] + Wb[(192 + h) * OUTc + o]);
            }
            Ews[(size_t)tok * OUTc + o] = ev;
        }
    }
}

// Kernel 2: tiled pair kernel. Grid (8, 32, 4): x = e-tile (64 e's),
// y = s-tile (16 s's), z = batch. Tiles fully below the diagonal exit.
// q/A tiles staged in LDS; each 4-lane group owns one e: k row (16 floats/lane)
// and E chunk live in REGISTERS across all 16 s-iterations. Inner loop is
// LDS-broadcast q + 16 FMA + 2 shfl + NT store -> HBM-write-bound.
__global__ __launch_bounds__(256) void pair_kernel(
    const float* __restrict__ qws, const float* __restrict__ kws,
    const float* __restrict__ Aws, const float* __restrict__ Ews,
    float* __restrict__ out)
{
    const int j = blockIdx.x;        // e-tile 0..7
    const int i = blockIdx.y;        // s-tile 0..31
    const int b = blockIdx.z;
    if (j < (i >> 2)) return;        // tile entirely below diagonal

    __shared__ alignas(16) float q_tile[16][64];
    __shared__ alignas(16) float A_tile[16][16];

    const int tid = threadIdx.x;
    const int s0 = i * 16;
    const int e0 = j * 64;

    // Stage q (16x64) and A (16x16) tiles, coalesced float4.
    {
        const int r = tid >> 4, c4 = tid & 15;
        ((float4*)q_tile[r])[c4] =
            ((const float4*)(qws + ((size_t)b * Lc + s0 + r) * HSc))[c4];
        if (tid < 64) {
            const int ra = tid >> 2, ca = tid & 3;
            ((float4*)A_tile[ra])[ca] =
                ((const float4*)(Aws + ((size_t)b * Lc + s0 + ra) * OUTc))[ca];
        }
    }
    __syncthreads();

    const int g = tid >> 2;          // group 0..63 -> e_local
    const int l = tid & 3;           // lane in group
    const int e = e0 + g;

    // k chunk scheme: lane l holds float4 indices {l, l+4, l+8, l+12}
    // -> per-instr lane addresses are 16B-contiguous within each group.
    const float4* kk = (const float4*)(kws + ((size_t)b * Lc + e) * HSc);
    const float4 kv0 = kk[l];
    const float4 kv1 = kk[4 + l];
    const float4 kv2 = kk[8 + l];
    const float4 kv3 = kk[12 + l];
    const float4 ev  = ((const float4*)(Ews + ((size_t)b * Lc + e) * OUTc))[l];

    float* ob = out + (size_t)b * Pc * OUTc;

    #pragma unroll 4
    for (int sl = 0; sl < 16; ++sl) {
        const int s = s0 + sl;
        const float4* qq = (const float4*)q_tile[sl];
        const float4 qv0 = qq[l];
        const float4 qv1 = qq[4 + l];
        const float4 qv2 = qq[8 + l];
        const float4 qv3 = qq[12 + l];

        float sc = qv0.x * kv0.x + qv0.y * kv0.y + qv0.z * kv0.z + qv0.w * kv0.w
                 + qv1.x * kv1.x + qv1.y * kv1.y + qv1.z * kv1.z + qv1.w * kv1.w
                 + qv2.x * kv2.x + qv2.y * kv2.y + qv2.z * kv2.z + qv2.w * kv2.w
                 + qv3.x * kv3.x + qv3.y * kv3.y + qv3.z * kv3.z + qv3.w * kv3.w;
        sc += __shfl_xor(sc, 1);
        sc += __shfl_xor(sc, 2);

        if (e >= s) {
            const float4 av = ((const float4*)A_tile[sl])[l];
            const int row = s * (2 * Lc + 1 - s) / 2 + (e - s);
            floatx4 r;
            r.x = av.x + ev.x + sc;
            r.y = av.y + ev.y + sc;
            r.z = av.z + ev.z + sc;
            r.w = av.w + ev.w + sc;
            __builtin_nontemporal_store(r, (floatx4*)(ob + (size_t)row * OUTc) + l);
        }
    }
}

extern "C" void kernel_launch(void* const* d_in, const int* in_sizes, int n_in,
                              void* d_out, int out_size, void* d_ws, size_t ws_size,
                              hipStream_t stream) {
    const float* x  = (const float*)d_in[0];
    const float* Wq = (const float*)d_in[1];
    const float* bq = (const float*)d_in[2];
    const float* Wk = (const float*)d_in[3];
    const float* bk = (const float*)d_in[4];
    const float* Wb = (const float*)d_in[5];
    const float* bb = (const float*)d_in[6];

    float* ws  = (float*)d_ws;
    float* qws = ws;
    float* kws = ws + 131072;
    float* Aws = ws + 262144;
    float* Ews = ws + 294912;

    qk_proj_kernel<<<dim3(256), dim3(512), 0, stream>>>(
        x, Wq, bq, Wk, bk, Wb, bb, qws, kws, Aws, Ews);
    pair_kernel<<<dim3(8, 32, 4), dim3(256), 0, stream>>>(
        qws, kws, Aws, Ews, (float*)d_out);
}

// Round 6
// 101.224 us; speedup vs baseline: 1.0751x; 1.0751x over previous
//
#include <hip/hip_runtime.h>
#include <hip/hip_bf16.h>

// Problem constants (B, L, H, HS, OUT) = (4, 512, 768, 64, 16)
#define Bc   4
#define Lc   512
#define Hc   768
#define HSc  64
#define OUTc 16
#define Pc   131328   // L*(L+1)/2
#define KSEG 192      // K quarter (768/4)

typedef float floatx4 __attribute__((ext_vector_type(4)));

// Workspace layout (floats): q@0, k@131072, A@262144, E@294912

// Kernel 1 (== Round-4 version, best measured): fused q/k projection + A/E.
// Grid: 512 blocks x 512 threads (8 waves); block = 4 tokens -> 2 blocks/CU,
// 4 waves/SIMD. Wave wu: half = wu&1 (q/k), kseg = wu>>1.
// Double-buffered 16-deep W prefetch; x loads wave-uniform -> scalar s_load.
__global__ __launch_bounds__(512, 4) void qk_proj_kernel(
    const float* __restrict__ x,
    const float* __restrict__ Wq, const float* __restrict__ bq,
    const float* __restrict__ Wk, const float* __restrict__ bk,
    const float* __restrict__ Wb, const float* __restrict__ bb,
    float* __restrict__ qws, float* __restrict__ kws,
    float* __restrict__ Aws, float* __restrict__ Ews)
{
    __shared__ float lds_p[4][4][128];   // [kseg][local token][q(0..63)|k(64..127)]
    __shared__ float lds_c[4][128];      // combined q|k per token

    const int tid = threadIdx.x;
    const int wu  = __builtin_amdgcn_readfirstlane(tid >> 6);  // wave id 0..7
    const int half = wu & 1;                                   // 0=q, 1=k
    const int kseg = wu >> 1;                                  // 0..3
    const int col  = tid & 63;
    const int tok_base = blockIdx.x * 4;

    const float* Wp = half ? Wk : Wq;                          // wave-uniform
    const float* wp = Wp + (size_t)kseg * KSEG * HSc + col;
    const float* xr = x + (size_t)tok_base * Hc + kseg * KSEG; // uniform -> s_load

    float acc0 = 0.f, acc1 = 0.f, acc2 = 0.f, acc3 = 0.f;
    float wA[16], wB[16];

    #pragma unroll
    for (int u = 0; u < 16; ++u) wA[u] = wp[u * HSc];

    #pragma unroll 1
    for (int j0 = 0; j0 < KSEG; j0 += 32) {
        #pragma unroll
        for (int u = 0; u < 16; ++u) wB[u] = wp[(j0 + 16 + u) * HSc];
        #pragma unroll
        for (int u = 0; u < 16; ++u) {
            const int jj = j0 + u;
            const float x0 = xr[jj];
            const float x1 = xr[Hc + jj];
            const float x2 = xr[2 * Hc + jj];
            const float x3 = xr[3 * Hc + jj];
            acc0 += x0 * wA[u];
            acc1 += x1 * wA[u];
            acc2 += x2 * wA[u];
            acc3 += x3 * wA[u];
        }
        if (j0 + 32 < KSEG) {
            #pragma unroll
            for (int u = 0; u < 16; ++u) wA[u] = wp[(j0 + 32 + u) * HSc];
        }
        #pragma unroll
        for (int u = 0; u < 16; ++u) {
            const int jj = j0 + 16 + u;
            const float x0 = xr[jj];
            const float x1 = xr[Hc + jj];
            const float x2 = xr[2 * Hc + jj];
            const float x3 = xr[3 * Hc + jj];
            acc0 += x0 * wB[u];
            acc1 += x1 * wB[u];
            acc2 += x2 * wB[u];
            acc3 += x3 * wB[u];
        }
    }

    const int n = half * 64 + col;
    lds_p[kseg][0][n] = acc0;
    lds_p[kseg][1][n] = acc1;
    lds_p[kseg][2][n] = acc2;
    lds_p[kseg][3][n] = acc3;
    __syncthreads();

    if (tid < 512) {
        const int t = tid >> 7;
        const int c = tid & 127;
        float v = lds_p[0][t][c] + lds_p[1][t][c] + lds_p[2][t][c] + lds_p[3][t][c];
        const int cc = c & 63;
        if (c < 64) { v += bq[cc]; qws[(size_t)(tok_base + t) * HSc + cc] = v; }
        else        { v += bk[cc]; kws[(size_t)(tok_base + t) * HSc + cc] = v; }
        lds_c[t][c] = v;
    }
    __syncthreads();

    // Phase B: A[t] = q@Wb[0:64]; E[t] = q@Wb[128:192] + k@(Wb[64:128]+Wb[192:256]) + bb
    if (tid < 128) {
        const int t = tid >> 5;
        const int c = tid & 31;
        const int tok = tok_base + t;
        const float* row = lds_c[t];
        if (c < 16) {
            float a = 0.f;
            #pragma unroll 8
            for (int h = 0; h < 64; ++h)
                a += row[h] * Wb[h * OUTc + c];
            Aws[(size_t)tok * OUTc + c] = a;
        } else {
            const int o = c - 16;
            float ev = bb[o];
            #pragma unroll 8
            for (int h = 0; h < 64; ++h) {
                ev += row[h]      * Wb[(128 + h) * OUTc + o];
                ev += row[64 + h] * (Wb[(64 + h) * OUTc + o] + Wb[(192 + h) * OUTc + o]);
            }
            Ews[(size_t)tok * OUTc + o] = ev;
        }
    }
}

// Kernel 2 (== Round-5 tiled version, unroll 8): Grid (8, 32, 4): x = e-tile
// (64 e's), y = s-tile (16 s's), z = batch. Tiles below diagonal exit early.
// q/A tiles in LDS; each 4-lane group owns one e with k row + E chunk in
// REGISTERS across all 16 s-iterations -> inner loop = LDS broadcast + FMA +
// 2 shfl + NT store.
__global__ __launch_bounds__(256) void pair_kernel(
    const float* __restrict__ qws, const float* __restrict__ kws,
    const float* __restrict__ Aws, const float* __restrict__ Ews,
    float* __restrict__ out)
{
    const int j = blockIdx.x;        // e-tile 0..7
    const int i = blockIdx.y;        // s-tile 0..31
    const int b = blockIdx.z;
    if (j < (i >> 2)) return;        // tile entirely below diagonal

    __shared__ alignas(16) float q_tile[16][64];
    __shared__ alignas(16) float A_tile[16][16];

    const int tid = threadIdx.x;
    const int s0 = i * 16;
    const int e0 = j * 64;

    {
        const int r = tid >> 4, c4 = tid & 15;
        ((float4*)q_tile[r])[c4] =
            ((const float4*)(qws + ((size_t)b * Lc + s0 + r) * HSc))[c4];
        if (tid < 64) {
            const int ra = tid >> 2, ca = tid & 3;
            ((float4*)A_tile[ra])[ca] =
                ((const float4*)(Aws + ((size_t)b * Lc + s0 + ra) * OUTc))[ca];
        }
    }
    __syncthreads();

    const int g = tid >> 2;          // group 0..63 -> e_local
    const int l = tid & 3;           // lane in group
    const int e = e0 + g;

    const float4* kk = (const float4*)(kws + ((size_t)b * Lc + e) * HSc);
    const float4 kv0 = kk[l];
    const float4 kv1 = kk[4 + l];
    const float4 kv2 = kk[8 + l];
    const float4 kv3 = kk[12 + l];
    const float4 ev  = ((const float4*)(Ews + ((size_t)b * Lc + e) * OUTc))[l];

    float* ob = out + (size_t)b * Pc * OUTc;

    #pragma unroll 8
    for (int sl = 0; sl < 16; ++sl) {
        const int s = s0 + sl;
        const float4* qq = (const float4*)q_tile[sl];
        const float4 qv0 = qq[l];
        const float4 qv1 = qq[4 + l];
        const float4 qv2 = qq[8 + l];
        const float4 qv3 = qq[12 + l];

        float sc = qv0.x * kv0.x + qv0.y * kv0.y + qv0.z * kv0.z + qv0.w * kv0.w
                 + qv1.x * kv1.x + qv1.y * kv1.y + qv1.z * kv1.z + qv1.w * kv1.w
                 + qv2.x * kv2.x + qv2.y * kv2.y + qv2.z * kv2.z + qv2.w * kv2.w
                 + qv3.x * kv3.x + qv3.y * kv3.y + qv3.z * kv3.z + qv3.w * kv3.w;
        sc += __shfl_xor(sc, 1);
        sc += __shfl_xor(sc, 2);

        if (e >= s) {
            const float4 av = ((const float4*)A_tile[sl])[l];
            const int row = s * (2 * Lc + 1 - s) / 2 + (e - s);
            floatx4 r;
            r.x = av.x + ev.x + sc;
            r.y = av.y + ev.y + sc;
            r.z = av.z + ev.z + sc;
            r.w = av.w + ev.w + sc;
            __builtin_nontemporal_store(r, (floatx4*)(ob + (size_t)row * OUTc) + l);
        }
    }
}

extern "C" void kernel_launch(void* const* d_in, const int* in_sizes, int n_in,
                              void* d_out, int out_size, void* d_ws, size_t ws_size,
                              hipStream_t stream) {
    const float* x  = (const float*)d_in[0];
    const float* Wq = (const float*)d_in[1];
    const float* bq = (const float*)d_in[2];
    const float* Wk = (const float*)d_in[3];
    const float* bk = (const float*)d_in[4];
    const float* Wb = (const float*)d_in[5];
    const float* bb = (const float*)d_in[6];

    float* ws  = (float*)d_ws;
    float* qws = ws;
    float* kws = ws + 131072;
    float* Aws = ws + 262144;
    float* Ews = ws + 294912;

    qk_proj_kernel<<<dim3(512), dim3(512), 0, stream>>>(
        x, Wq, bq, Wk, bk, Wb, bb, qws, kws, Aws, Ews);
    pair_kernel<<<dim3(8, 32, 4), dim3(256), 0, stream>>>(
        qws, kws, Aws, Ews, (float*)d_out);
}